// Round 7
// baseline (190.832 us; speedup 1.0000x reference)
//
#include <hip/hip_runtime.h>
#include <hip/hip_bf16.h>

#define B_   8
#define TQ_  100
#define TS_  100
#define E_   512
#define D_   512
#define K_   1024
#define M_   (B_*TQ_*TS_)   // 80000

#define BM   128            // M-tile per block (625 blocks)
#define BK   64             // K per step (16 steps)
#define NTHREADS 512        // 8 waves: 2M x 4N, wave tile 64x128

typedef __attribute__((ext_vector_type(4))) float f32x4;
typedef __attribute__((ext_vector_type(8))) short bf16x8;

__device__ __forceinline__ short f2bf(float f) {
  __hip_bfloat16 h = __float2bfloat16(f);
  return *reinterpret_cast<short*>(&h);
}

__device__ __forceinline__ float fast_tanh(float x) {
  float e = __expf(2.0f * x);
  return 1.0f - 2.0f / (e + 1.0f);
}

__device__ __forceinline__ void gld16(const void* g, void* l) {
  __builtin_amdgcn_global_load_lds(
      (const __attribute__((address_space(1))) unsigned int*)g,
      (__attribute__((address_space(3))) unsigned int*)l, 16, 0, 0);
}

// ---- prep: W1 [k=1024][n=512] f32 -> W1sw bf16 [n=512][k=1024], XOR-preswizzled
// within each 128B k-segment: element (n,k) at byte (k*2)^((n&7)<<4) of row n.
// gld16 stages rows LINEARLY; ds_read at (n*128 + (kb^((n&7)<<4))) is the
// measured-0-conflict layout (R1/R5/R6).
__global__ void prep_w1(const float* __restrict__ W1, short* __restrict__ W1sw) {
  int idx = blockIdx.x * 256 + threadIdx.x;   // over K_*D_
  int k = idx >> 9;
  int n = idx & (D_ - 1);
  int byte = (k * 2) ^ ((n & 7) << 4);
  W1sw[(size_t)n * K_ + (byte >> 1)] = f2bf(W1[idx]);
}

// ---- kernel 1: scores[m] = sum_n w2[n]*tanh(cat[m,:].W1[:,n] + b1[n]) ----
__launch_bounds__(NTHREADS, 2)
__global__ void scores_kernel(const float* __restrict__ src,
                              const float* __restrict__ tgt,
                              const short* __restrict__ W1sw,
                              const float* __restrict__ b1,
                              const float* __restrict__ w2,
                              float* __restrict__ scores) {
  __shared__ __align__(16) char Alds[2][BM * 128];   // 2 x 16 KB
  __shared__ __align__(16) char Blds[2][D_ * 128];   // 2 x 64 KB -> 160 KB total

  const int tid  = threadIdx.x;
  const int wave = tid >> 6;
  const int lane = tid & 63;
  const int lr   = lane & 15;
  const int lg   = lane >> 4;
  const int wr   = wave >> 2;      // 0..1 -> rows wr*64..+64
  const int wc   = wave & 3;       // 0..3 -> cols wc*128..+128
  const int m0   = blockIdx.x * BM;

  f32x4 acc[4][8];
  #pragma unroll
  for (int i = 0; i < 4; i++)
    #pragma unroll
    for (int j = 0; j < 8; j++)
      acc[i][j] = (f32x4){0.f, 0.f, 0.f, 0.f};

  // A staging: thread -> row ra (4 thr/row), 16 consecutive floats at kaf
  const int ra  = tid >> 2;                 // 0..127
  const int kaf = (tid & 3) * 16;           // 0,16,32,48
  const int asw = (ra & 7) << 4;
  const size_t arow = (size_t)(m0 + ra) * E_;

  #define SBAR0       __builtin_amdgcn_sched_barrier(0)
  #define WAIT_LGKM0  { asm volatile("s_waitcnt lgkmcnt(0)" ::: "memory"); SBAR0; }
  #define BARRIER     { __builtin_amdgcn_s_barrier(); SBAR0; }

  // B staging: wave (wr,wc) round R stages 8 rows at wc*128 + R*16 + wr*8.
  // LDS dest is wave-uniform; HW adds lane*16. Global src per-lane.
  #define ISSUE_B(R, KN, BNX)                                                  \
    { const int rb = wc * 128 + (R) * 16 + wr * 8;                             \
      gld16((const char*)W1sw + (size_t)(rb + (lane >> 3)) * 2048              \
                + (size_t)(KN) * 2 + (size_t)((lane & 7) * 16),                \
            (BNX) + rb * 128); }

  #define ISSUE_AF32(KN)                                                       \
    { const float* Ap = (((KN) < E_) ? src : tgt) + arow + ((KN) & (E_-1)) + kaf; \
      r0 = *(const f32x4*)(Ap);                                                \
      r1 = *(const f32x4*)(Ap + 4);                                            \
      r2 = *(const f32x4*)(Ap + 8);                                            \
      r3 = *(const f32x4*)(Ap + 12); }

  #define WRITE_A(BUF)                                                         \
    { bf16x8 w0, w1;                                                           \
      w0[0]=f2bf(r0[0]); w0[1]=f2bf(r0[1]); w0[2]=f2bf(r0[2]); w0[3]=f2bf(r0[3]); \
      w0[4]=f2bf(r1[0]); w0[5]=f2bf(r1[1]); w0[6]=f2bf(r1[2]); w0[7]=f2bf(r1[3]); \
      w1[0]=f2bf(r2[0]); w1[1]=f2bf(r2[1]); w1[2]=f2bf(r2[2]); w1[3]=f2bf(r2[3]); \
      w1[4]=f2bf(r3[0]); w1[5]=f2bf(r3[1]); w1[6]=f2bf(r3[2]); w1[7]=f2bf(r3[3]); \
      int kb = kaf * 2;                                                        \
      *(bf16x8*)((BUF) + ra * 128 + ( kb       ^ asw)) = w0;                   \
      *(bf16x8*)((BUF) + ra * 128 + ((kb + 16) ^ asw)) = w1; }

  #define RD_A(KK)                                                             \
    { _Pragma("unroll")                                                        \
      for (int mi = 0; mi < 4; mi++) {                                         \
        int row = wr * 64 + mi * 16 + lr;                                      \
        a[mi] = *(const bf16x8*)(Acur + row * 128 +                            \
                    (((KK) * 64 + lg * 16) ^ ((row & 7) << 4)));               \
      } }

  #define RD_B(KK, H)                                                          \
    { _Pragma("unroll")                                                        \
      for (int nn = 0; nn < 4; nn++) {                                         \
        int n = wc * 128 + ((H) * 4 + nn) * 16 + lr;                           \
        b[nn] = *(const bf16x8*)(Bcur + n * 128 +                              \
                    (((KK) * 64 + lg * 16) ^ ((n & 7) << 4)));                 \
      } }

  #define MFMA16(H)                                                            \
    { __builtin_amdgcn_s_setprio(1);                                           \
      _Pragma("unroll")                                                        \
      for (int mi = 0; mi < 4; mi++)                                           \
        _Pragma("unroll")                                                      \
        for (int nn = 0; nn < 4; nn++)                                         \
          acc[mi][(H) * 4 + nn] = __builtin_amdgcn_mfma_f32_16x16x32_bf16(     \
              a[mi], b[nn], acc[mi][(H) * 4 + nn], 0, 0, 0);                   \
      __builtin_amdgcn_s_setprio(0); }

  // ---- prologue: stage tile 0 fully, drain, barrier ----
  {
    f32x4 r0, r1, r2, r3;
    #pragma unroll
    for (int r = 0; r < 8; r++) ISSUE_B(r, 0, Blds[0]);
    ISSUE_AF32(0);
    asm volatile("s_waitcnt vmcnt(0)" ::: "memory"); SBAR0;
    WRITE_A(Alds[0]);
    WAIT_LGKM0;
    BARRIER;
  }

  for (int t = 0; t < 16; ++t) {
    char* Acur = Alds[t & 1];
    char* Anxt = Alds[(t + 1) & 1];
    char* Bcur = Blds[t & 1];
    char* Bnxt = Blds[(t + 1) & 1];
    const bool pf = (t < 15);
    const int kn  = (t + 1) * BK;
    bf16x8 a[4], b[4];
    f32x4 r0, r1, r2, r3;

    // ---- phase 0: a(kk0) + b(kk0,ni0-3); issue B rounds 0,1 ----
    RD_A(0);
    RD_B(0, 0);
    if (pf) {
      ISSUE_B(0, kn, Bnxt); ISSUE_B(1, kn, Bnxt);
      asm volatile("s_waitcnt vmcnt(2)" ::: "memory"); SBAR0;  // prev r4-7 landed
    } else {
      asm volatile("s_waitcnt vmcnt(0)" ::: "memory"); SBAR0;
    }
    BARRIER; WAIT_LGKM0;
    MFMA16(0);
    BARRIER;

    // ---- phase 1: b(kk0,ni4-7); issue B rounds 2,3 + A f32 ----
    RD_B(0, 1);
    if (pf) {
      ISSUE_B(2, kn, Bnxt); ISSUE_B(3, kn, Bnxt);
      ISSUE_AF32(kn);
    }
    BARRIER; WAIT_LGKM0;
    MFMA16(1);
    BARRIER;

    // ---- phase 2: a(kk1) + b(kk1,ni0-3); issue B rounds 4,5 ----
    RD_A(1);
    RD_B(1, 0);
    if (pf) { ISSUE_B(4, kn, Bnxt); ISSUE_B(5, kn, Bnxt); }
    BARRIER; WAIT_LGKM0;
    MFMA16(0 + 2 - 2);   // kk1, ni0-3 -> acc[][0..3]
    BARRIER;

    // ---- phase 3: b(kk1,ni4-7); issue B rounds 6,7; drain A + r0-3; write A ----
    RD_B(1, 1);
    if (pf) {
      ISSUE_B(6, kn, Bnxt); ISSUE_B(7, kn, Bnxt);
      asm volatile("s_waitcnt vmcnt(4)" ::: "memory"); SBAR0;  // A f32 + r0-3 landed
      WRITE_A(Anxt);
    }
    BARRIER; WAIT_LGKM0;
    MFMA16(1);
    BARRIER;
  }

  // ---- epilogue: scores[m] = sum_n w2[n]*tanh(h[m,n]+b1[n]) ----
  float* s_sc = (float*)Alds;   // done with A buffers
  if (tid < BM) s_sc[tid] = 0.0f;
  __syncthreads();

  float b1v[8], w2v[8];
  #pragma unroll
  for (int ni = 0; ni < 8; ni++) {
    int n = wc * 128 + ni * 16 + lr;
    b1v[ni] = b1[n];
    w2v[ni] = w2[n];
  }
  #pragma unroll
  for (int mi = 0; mi < 4; mi++) {
    #pragma unroll
    for (int r = 0; r < 4; r++) {
      float p = 0.0f;
      #pragma unroll
      for (int ni = 0; ni < 8; ni++)
        p += fast_tanh(acc[mi][ni][r] + b1v[ni]) * w2v[ni];
      p += __shfl_xor(p, 1);
      p += __shfl_xor(p, 2);
      p += __shfl_xor(p, 4);
      p += __shfl_xor(p, 8);
      if (lr == 0) atomicAdd(&s_sc[wr * 64 + mi * 16 + lg * 4 + r], p);
    }
  }
  __syncthreads();
  if (tid < BM) scores[m0 + tid] = s_sc[tid];
}

// ---- kernel 2: mask, softmax over s, weights out, weighted sum over src ----
__global__ void softmax_wsum(const float* __restrict__ src,
                             const float* __restrict__ mask,
                             const float* __restrict__ scores,
                             float* __restrict__ out) {
  const int row = blockIdx.x;     // b*TQ+q, 0..799
  const int tid = threadIdx.x;    // 512 threads
  __shared__ float s_e[TS_];

  float v = 0.0f;
  if (tid < TS_) {
    v = scores[row * TS_ + tid] * mask[row * TS_ + tid];
    s_e[tid] = v;
  }
  __syncthreads();
  float mx = -3.0e38f;
  for (int s = 0; s < TS_; s++) mx = fmaxf(mx, s_e[s]);
  __syncthreads();
  if (tid < TS_) s_e[tid] = __expf(v - mx);
  __syncthreads();
  float sum = 0.0f;
  for (int s = 0; s < TS_; s++) sum += s_e[s];
  const float inv = 1.0f / sum;

  float* out_attn = out;                          // [800][512]
  float* out_w    = out + (size_t)B_ * TQ_ * E_;  // [800][100]
  if (tid < TS_) out_w[row * TS_ + tid] = s_e[tid] * inv;

  const float* sp = src + (size_t)row * TS_ * E_ + tid;
  float acc = 0.0f;
  #pragma unroll 4
  for (int s = 0; s < TS_; s++) acc = fmaf(s_e[s], sp[(size_t)s * E_], acc);
  out_attn[row * E_ + tid] = acc * inv;
}

extern "C" void kernel_launch(void* const* d_in, const int* in_sizes, int n_in,
                              void* d_out, int out_size, void* d_ws, size_t ws_size,
                              hipStream_t stream) {
  const float* src  = (const float*)d_in[0];
  const float* tgt  = (const float*)d_in[1];
  const float* mask = (const float*)d_in[2];
  const float* W1   = (const float*)d_in[3];
  const float* b1   = (const float*)d_in[4];
  const float* w2   = (const float*)d_in[5];

  short* W1sw   = (short*)d_ws;                                // 1 MB
  float* scores = (float*)((char*)d_ws + (size_t)D_ * K_ * 2); // 80000 f32

  float* out = (float*)d_out;

  hipLaunchKernelGGL(prep_w1, dim3((K_ * D_) / 256), dim3(256), 0, stream, W1, W1sw);
  hipLaunchKernelGGL(scores_kernel, dim3(M_ / BM), dim3(NTHREADS), 0, stream,
                     src, tgt, W1sw, b1, w2, scores);
  hipLaunchKernelGGL(softmax_wsum, dim3(B_ * TQ_), dim3(512), 0, stream,
                     src, mask, scores, out);
}